// Round 5
// baseline (717.589 us; speedup 1.0000x reference)
//
#include <hip/hip_runtime.h>

#define NBS    256
#define NELEC  64
#define NPART  80
#define NBASIS 32
#define KD     128
#define DD     128
#define IB     8     // i's per cfconv block

typedef short v8s __attribute__((ext_vector_type(8)));
typedef float v4f __attribute__((ext_vector_type(4)));

// fast shifted softplus: log(1+e^x) - ln2 via HW exp2/log2 (inputs bounded, |x| << 88)
__device__ __forceinline__ float sspf(float x) {
    float t = __expf(x);
    return __logf(1.0f + t) - 0.69314718055994530942f;
}

__device__ __forceinline__ float bf2f(unsigned short u) {
    unsigned int x = ((unsigned int)u) << 16;
    return __builtin_bit_cast(float, x);
}
__device__ __forceinline__ unsigned short f2bf(float f) {
    unsigned int x = __builtin_bit_cast(unsigned int, f);
    x += 0x7fffu + ((x >> 16) & 1u);
    return (unsigned short)(x >> 16);
}
__device__ __forceinline__ unsigned int pk2(float lo, float hi) {
    return (unsigned int)f2bf(lo) | ((unsigned int)f2bf(hi) << 16);
}

// xs[b,i,:] = embedding_elec[i,:] (f32 master + bf16 mirror)
__global__ __launch_bounds__(256) void k_init_xs(const float* __restrict__ emb,
                                                 float* __restrict__ xs,
                                                 unsigned short* __restrict__ xs_bf) {
    int idx = blockIdx.x * 256 + threadIdx.x;
    float v = emb[idx & (NELEC * DD - 1)];
    xs[idx] = v;
    xs_bf[idx] = f2bf(v);
}

// Pre-swizzle kW1/kW2/eiW (per layer) into MFMA A-operand fragment order, bf16.
// A-frag: lane holds A[m = lane&15][k = (lane>>4)*8 + jj], jj=0..7.
// kW2Tf/eiWTf layout: [l][mt'(8)][ks(4)][lane(64)][jj(8)]  (A'[kcol][kf] = W[kf][kcol])
// kW1Tf layout:       [l][kct(8)][lane(64)][jj(8)]         (A'[kcol][f]  = kW1[f][kcol])
__global__ __launch_bounds__(256) void k_prep(const float* __restrict__ kW1g,
                                              const float* __restrict__ kW2g,
                                              const float* __restrict__ eiWg,
                                              unsigned short* __restrict__ kW1Tf,
                                              unsigned short* __restrict__ kW2Tf,
                                              unsigned short* __restrict__ eiWTf) {
    const int l = blockIdx.x;
    const int t = threadIdx.x;
    for (int e = 0; e < 64; ++e) {
        int o = e * 256 + t;                       // < 16384
        int mt = o >> 11, ks = (o >> 9) & 3, lane = (o >> 3) & 63, jj = o & 7;
        int q = lane >> 4, cc = lane & 15;
        int kf = ks * 32 + q * 8 + jj;
        int kcol = mt * 16 + cc;
        kW2Tf[(size_t)l * 16384 + o] = f2bf(kW2g[(size_t)l * 16384 + kf * 128 + kcol]);
        eiWTf[(size_t)l * 16384 + o] = f2bf(eiWg[(size_t)l * 16384 + kf * 128 + kcol]);
    }
    for (int e = 0; e < 16; ++e) {
        int o = e * 256 + t;                       // < 4096
        int kct = o >> 9, lane = (o >> 3) & 63, jj = o & 7;
        int q = lane >> 4, cc = lane & 15;
        int f = q * 8 + jj;
        int kcol = kct * 16 + cc;
        kW1Tf[(size_t)l * 4096 + o] = f2bf(kW1g[(size_t)l * 4096 + f * 128 + kcol]);
    }
}

// B-operand fragment swizzle for the out-MLP weights (6 matrices 128x128).
// Wf[bi][mt(8)][ks(4)][lane(64)][jj(8)] = W[ks*32+q*8+jj][mt*16+c]; bi = which*3 + l
__global__ __launch_bounds__(256) void k_prep_w(const float* __restrict__ eoW1,
                                                const float* __restrict__ eoW2,
                                                unsigned short* __restrict__ Wf) {
    const int bi = blockIdx.x;          // 0..5
    const int which = bi / 3, l = bi % 3;
    const float* src = (which == 0 ? eoW1 : eoW2) + (size_t)l * 16384;
    unsigned short* dst = Wf + (size_t)bi * 16384;
    const int t = threadIdx.x;
    for (int e = 0; e < 64; ++e) {
        int o = e * 256 + t;
        int mt = o >> 11, ks = (o >> 9) & 3, lane = (o >> 3) & 63, jj = o & 7;
        int q = lane >> 4, cc = lane & 15;
        dst[o] = f2bf(src[(ks * 32 + q * 8 + jj) * 128 + mt * 16 + cc]);
    }
}

// bias fragments for cfconv + nuc bf16 table:
// kb1f/kb2f: [l][w(4)][lane(64)][e(8)], e=mt*4+r -> kb[l*128 + (2*w+mt)*16 + q*4 + r]
__global__ __launch_bounds__(256) void k_prep_misc(const float* __restrict__ kb1,
                                                   const float* __restrict__ kb2,
                                                   const float* __restrict__ emb_n,
                                                   float* __restrict__ kb1f,
                                                   float* __restrict__ kb2f,
                                                   unsigned short* __restrict__ nucbf) {
    const int t = threadIdx.x;
    for (int o = t; o < 3 * 4 * 64 * 8; o += 256) {
        int l = o >> 11, rem = o & 2047;
        int w = rem >> 9, lane = (rem >> 3) & 63, e = o & 7;
        int mt = e >> 2, r = e & 3, q = lane >> 4;
        int kcol = (2 * w + mt) * 16 + q * 4 + r;
        kb1f[o] = kb1[l * 128 + kcol];
        kb2f[o] = kb2[l * 128 + kcol];
    }
    for (int o = t; o < 16 * 128; o += 256) nucbf[o] = f2bf(emb_n[o]);
}

// Fused output MLP, one block per b:
//   h = ssp(agg @ eoW1 + eob1)   (LDS handoff, stride 136 shorts = conflict-free)
//   xs += h @ eoW2 + eob2        (f32 master + bf16 mirror)
__global__ __launch_bounds__(256) void k_outmlp(
    const unsigned short* __restrict__ aggbf,
    const unsigned short* __restrict__ Wf1, const float* __restrict__ eob1,
    const unsigned short* __restrict__ Wf2, const float* __restrict__ eob2,
    unsigned short* __restrict__ xs_bf, float* __restrict__ xs) {
    __shared__ __align__(16) unsigned short s_h[64 * 136];
    const int b = blockIdx.x;
    const int t = threadIdx.x, lane = t & 63, w = t >> 6;
    const int q = lane >> 4, c = lane & 15;

    // phase 1: h rows w*16..+15
    {
        const unsigned short* ab = aggbf + (size_t)b * (NELEC * KD);
        v8s A[4];
#pragma unroll
        for (int ks = 0; ks < 4; ++ks)
            A[ks] = *(const v8s*)(ab + (w * 16 + c) * 128 + ks * 32 + q * 8);
#pragma unroll
        for (int kt = 0; kt < 8; ++kt) {
            float bv = eob1[kt * 16 + c];
            v4f acc = {bv, bv, bv, bv};
#pragma unroll
            for (int ks = 0; ks < 4; ++ks) {
                v8s B = *(const v8s*)(Wf1 + (((size_t)kt * 4 + ks) * 64 + lane) * 8);
                acc = __builtin_amdgcn_mfma_f32_16x16x32_bf16(A[ks], B, acc, 0, 0, 0);
            }
#pragma unroll
            for (int r = 0; r < 4; ++r)
                s_h[(w * 16 + q * 4 + r) * 136 + kt * 16 + c] = f2bf(sspf(acc[r]));
        }
    }
    __syncthreads();
    // phase 2: xs update rows w*16..+15
    {
        v8s H[4];
#pragma unroll
        for (int ks = 0; ks < 4; ++ks)
            H[ks] = *(const v8s*)(s_h + (w * 16 + c) * 136 + ks * 32 + q * 8);
#pragma unroll
        for (int kt = 0; kt < 8; ++kt) {
            float bv = eob2[kt * 16 + c];
            v4f acc = {bv, bv, bv, bv};
#pragma unroll
            for (int ks = 0; ks < 4; ++ks) {
                v8s B = *(const v8s*)(Wf2 + (((size_t)kt * 4 + ks) * 64 + lane) * 8);
                acc = __builtin_amdgcn_mfma_f32_16x16x32_bf16(H[ks], B, acc, 0, 0, 0);
            }
#pragma unroll
            for (int r = 0; r < 4; ++r) {
                size_t o = (size_t)b * (NELEC * KD) + (w * 16 + q * 4 + r) * 128 + kt * 16 + c;
                float nv = xs[o] + acc[r];
                xs[o] = nv;
                xs_bf[o] = f2bf(nv);
            }
        }
    }
}

// One block per (b, group of IB i's). Transposed MFMA formulation; wave w owns
// kcols [w*32, w*32+32). Prelude: stage ALL IB dists tiles to LDS, compute
// zsT via MFMA from xs_bf/eiWT (C-layout lands in zf reduce positions), load
// weights. Loop: 1 barrier per i; GEMM1(ii+1) overlaps GEMM2(ii) epilogue.
__global__ __launch_bounds__(256, 2) void k_cfconv_mfma(
    const float* __restrict__ dists,
    const float* __restrict__ kb1f, const float* __restrict__ kb2f,
    const unsigned short* __restrict__ xs_bf,
    const unsigned short* __restrict__ nucbf,
    const unsigned short* __restrict__ kW1Tf,
    const unsigned short* __restrict__ kW2Tf,
    const unsigned short* __restrict__ eiWTf,
    unsigned short* __restrict__ aggbf, int l) {
    __shared__ __align__(16) unsigned short s_dall[IB * 5 * 64 * 8];  // 40960 B
    __shared__ __align__(16) unsigned short s_X1[2 * 10240];          // 40960 B

    const int blk = blockIdx.x;
    const int b = blk >> 3;
    const int ig = blk & 7;
    const int t = threadIdx.x;
    const int lane = t & 63;
    const int w = t >> 6;
    const int q = lane >> 4;
    const int c = lane & 15;

    // --- stage all IB dists tiles into B-frag order (issue loads early) ---
    {
        const float* dbase = dists + ((size_t)b * NELEC + ig * IB) * (NPART * NBASIS);
#pragma unroll
        for (int e = 0; e < 10; ++e) {
            int tile = e * 4 + w;               // 0..39 = i2*5 + jt
            int i2 = tile / 5, jt = tile % 5;
            const float* dj = dbase + i2 * 2560 + (jt * 16 + c) * 32 + q * 8;
            float4 v0 = *(const float4*)dj;
            float4 v1 = *(const float4*)(dj + 4);
            uint4 pk;
            pk.x = pk2(v0.x, v0.y);
            pk.y = pk2(v0.z, v0.w);
            pk.z = pk2(v1.x, v1.y);
            pk.w = pk2(v1.z, v1.w);
            *(uint4*)(s_dall + (tile * 64 + lane) * 8) = pk;
        }
    }

    // --- weights + biases ---
    v8s a1[2], a2[2][4];
    {
        const uint4* w1p = (const uint4*)kW1Tf;
        const uint4* w2p = (const uint4*)kW2Tf;
#pragma unroll
        for (int t1 = 0; t1 < 2; ++t1) {
            uint4 u = w1p[(l * 8 + 2 * w + t1) * 64 + lane];
            a1[t1] = __builtin_bit_cast(v8s, u);
        }
#pragma unroll
        for (int mt = 0; mt < 2; ++mt)
#pragma unroll
            for (int ks = 0; ks < 4; ++ks) {
                uint4 u = w2p[((l * 8 + 2 * w + mt) * 4 + ks) * 64 + lane];
                a2[mt][ks] = __builtin_bit_cast(v8s, u);
            }
    }
    float4 kb1v[2], kb2v[2];
    {
        const float4* p1 = (const float4*)(kb1f + ((size_t)(l * 4 + w) * 64 + lane) * 8);
        kb1v[0] = p1[0];
        kb1v[1] = p1[1];
        const float4* p2 = (const float4*)(kb2f + ((size_t)(l * 4 + w) * 64 + lane) * 8);
        kb2v[0] = p2[0];
        kb2v[1] = p2[1];
    }

    // --- zsT via MFMA: zf[mt][jt][r] = zs[j=jt*16+c][kcol=w*32+mt*16+q*4+r] ---
    float zf[2][5][4];
    {
        const uint4* wep = (const uint4*)eiWTf;
        v8s ae0[4], ae1[4];
#pragma unroll
        for (int ks = 0; ks < 4; ++ks) {
            uint4 u0 = wep[((l * 8 + 2 * w + 0) * 4 + ks) * 64 + lane];
            uint4 u1 = wep[((l * 8 + 2 * w + 1) * 4 + ks) * 64 + lane];
            ae0[ks] = __builtin_bit_cast(v8s, u0);
            ae1[ks] = __builtin_bit_cast(v8s, u1);
        }
        const unsigned short* xb = xs_bf + (size_t)b * (NELEC * KD);
#pragma unroll
        for (int jt = 0; jt < 4; ++jt) {
            v4f z0 = {0.f, 0.f, 0.f, 0.f}, z1 = {0.f, 0.f, 0.f, 0.f};
#pragma unroll
            for (int ks = 0; ks < 4; ++ks) {
                v8s bxs = *(const v8s*)(xb + (jt * 16 + c) * 128 + ks * 32 + q * 8);
                z0 = __builtin_amdgcn_mfma_f32_16x16x32_bf16(ae0[ks], bxs, z0, 0, 0, 0);
                z1 = __builtin_amdgcn_mfma_f32_16x16x32_bf16(ae1[ks], bxs, z1, 0, 0, 0);
            }
#pragma unroll
            for (int r = 0; r < 4; ++r) {
                zf[0][jt][r] = z0[r];
                zf[1][jt][r] = z1[r];
            }
        }
#pragma unroll
        for (int mt = 0; mt < 2; ++mt) {
            ushort4 zv = *(const ushort4*)(nucbf + c * 128 + w * 32 + mt * 16 + q * 4);
            zf[mt][4][0] = bf2f(zv.x);
            zf[mt][4][1] = bf2f(zv.y);
            zf[mt][4][2] = bf2f(zv.z);
            zf[mt][4][3] = bf2f(zv.w);
        }
    }
    __syncthreads();

    // GEMM1 for dists tile iidx -> s_X1 buffer xbuf (10 MFMA + ssp + pack)
    auto gemm1 = [&](int iidx, unsigned short* xbuf) {
#pragma unroll
        for (int jt = 0; jt < 5; ++jt) {
            v8s bd = *(const v8s*)(s_dall + ((iidx * 5 + jt) * 64 + lane) * 8);
#pragma unroll
            for (int t1 = 0; t1 < 2; ++t1) {
                v4f d = {kb1v[t1].x, kb1v[t1].y, kb1v[t1].z, kb1v[t1].w};
                d = __builtin_amdgcn_mfma_f32_16x16x32_bf16(a1[t1], bd, d, 0, 0, 0);
                uint2 o;
                o.x = pk2(sspf(d[0]), sspf(d[1]));
                o.y = pk2(sspf(d[2]), sspf(d[3]));
                int qB = 2 * t1 + (q >> 1);   // ks slice = w (wave owns kcols w*32..)
                *(uint2*)(xbuf + ((jt * 4 + w) * 64 + qB * 16 + c) * 8 + (q & 1) * 4) = o;
            }
        }
    };

    gemm1(0, s_X1);
    __syncthreads();

#pragma unroll 1
    for (int ii = 0; ii < IB; ++ii) {
        const int i = ig * IB + ii;
        const unsigned short* xcur = s_X1 + (ii & 1) * 10240;

        // GEMM2-T: 40 MFMA over (2 mt, 5 jt, 4 ks), full K sum per wave
        v4f acc[2][5];
#pragma unroll
        for (int mt = 0; mt < 2; ++mt)
#pragma unroll
            for (int jt = 0; jt < 5; ++jt)
                acc[mt][jt] = (v4f){(&kb2v[mt].x)[0], (&kb2v[mt].x)[1],
                                    (&kb2v[mt].x)[2], (&kb2v[mt].x)[3]};
#pragma unroll
        for (int jt = 0; jt < 5; ++jt) {
#pragma unroll
            for (int ks = 0; ks < 4; ++ks) {
                v8s bx = *(const v8s*)(xcur + ((jt * 4 + ks) * 64 + lane) * 8);
                acc[0][jt] = __builtin_amdgcn_mfma_f32_16x16x32_bf16(a2[0][ks], bx, acc[0][jt], 0, 0, 0);
                acc[1][jt] = __builtin_amdgcn_mfma_f32_16x16x32_bf16(a2[1][ks], bx, acc[1][jt], 0, 0, 0);
            }
        }

        // next i's GEMM1 (independent) — overlaps the reduce/butterfly below
        if (ii < IB - 1) gemm1(ii + 1, s_X1 + ((ii + 1) & 1) * 10240);

        // mask j==i, multiply by zs, reduce over j
        float red[8];
#pragma unroll
        for (int v = 0; v < 8; ++v) red[v] = 0.0f;
#pragma unroll
        for (int jt = 0; jt < 5; ++jt) {
            const bool dead = (jt * 16 + c) == i;
#pragma unroll
            for (int mt = 0; mt < 2; ++mt)
#pragma unroll
                for (int r = 0; r < 4; ++r) {
                    float a = dead ? 0.0f : acc[mt][jt][r];
                    red[mt * 4 + r] += a * zf[mt][jt][r];
                }
        }

        // butterfly: 8 vals -> lane c holds value (c&7), then xor-8 completes j-sum
        float vals[8];
#pragma unroll
        for (int v = 0; v < 8; ++v) vals[v] = red[v];
#pragma unroll
        for (int B = 0; B < 3; ++B) {
            const int off = 1 << B;
            const bool up = (c >> B) & 1;
#pragma unroll
            for (int k2 = 0; k2 < (4 >> B); ++k2) {
                float aa = vals[2 * k2], bb = vals[2 * k2 + 1];
                float mine = up ? bb : aa;
                float other = up ? aa : bb;
                vals[k2] = mine + __shfl_xor(other, off, 64);
            }
        }
        float x = vals[0] + __shfl_xor(vals[0], 8, 64);

        if (c < 8) {
            int kcol = w * 32 + ((c >> 2) & 1) * 16 + q * 4 + (c & 3);
            aggbf[((size_t)b * NELEC + i) * 128 + kcol] = f2bf(x);
        }

        if (ii < IB - 1) __syncthreads();
    }
}

extern "C" void kernel_launch(void* const* d_in, const int* in_sizes, int n_in,
                              void* d_out, int out_size, void* d_ws, size_t ws_size,
                              hipStream_t stream) {
    const float* dists = (const float*)d_in[0];
    const float* emb_e = (const float*)d_in[1];
    const float* emb_n = (const float*)d_in[2];
    const float* kW1   = (const float*)d_in[3];
    const float* kb1   = (const float*)d_in[4];
    const float* kW2   = (const float*)d_in[5];
    const float* kb2   = (const float*)d_in[6];
    const float* eiW   = (const float*)d_in[7];
    const float* eoW1  = (const float*)d_in[8];
    const float* eob1  = (const float*)d_in[9];
    const float* eoW2  = (const float*)d_in[10];
    const float* eob2  = (const float*)d_in[11];

    float* xs = (float*)d_out;                                  // (256,64,128) f32
    unsigned short* aggbf = (unsigned short*)d_ws;              // (256,64,128) bf16
    unsigned short* xs_bf = aggbf + NBS * NELEC * KD;           // (256,64,128) bf16
    unsigned short* kW1Tf = xs_bf + NBS * NELEC * KD;           // 3*4096
    unsigned short* kW2Tf = kW1Tf + 3 * 4096;                   // 3*16384
    unsigned short* eiWTf = kW2Tf + 3 * 16384;                  // 3*16384
    unsigned short* Wf    = eiWTf + 3 * 16384;                  // 6*16384
    float* kb1f = (float*)(Wf + 6 * 16384);                     // 6144 f32
    float* kb2f = kb1f + 6144;                                  // 6144 f32
    unsigned short* nucbf = (unsigned short*)(kb2f + 6144);     // 2048

    k_init_xs<<<(NBS * NELEC * DD) / 256, 256, 0, stream>>>(emb_e, xs, xs_bf);
    k_prep<<<3, 256, 0, stream>>>(kW1, kW2, eiW, kW1Tf, kW2Tf, eiWTf);
    k_prep_w<<<6, 256, 0, stream>>>(eoW1, eoW2, Wf);
    k_prep_misc<<<1, 256, 0, stream>>>(kb1, kb2, emb_n, kb1f, kb2f, nucbf);

    for (int l = 0; l < 3; ++l) {
        k_cfconv_mfma<<<NBS * (NELEC / IB), 256, 0, stream>>>(
            dists, kb1f, kb2f, xs_bf, nucbf, kW1Tf, kW2Tf, eiWTf, aggbf, l);

        k_outmlp<<<NBS, 256, 0, stream>>>(
            aggbf, Wf + (size_t)(0 * 3 + l) * 16384, eob1 + l * DD,
            Wf + (size_t)(1 * 3 + l) * 16384, eob2 + l * DD, xs_bf, xs);
    }
}